// Round 10
// baseline (222.683 us; speedup 1.0000x reference)
//
#include <hip/hip_runtime.h>

typedef _Float16 half8 __attribute__((ext_vector_type(8)));
typedef _Float16 half4 __attribute__((ext_vector_type(4)));
typedef _Float16 half2v __attribute__((ext_vector_type(2)));
typedef float floatx4 __attribute__((ext_vector_type(4)));

// Problem constants: B=2, N=2048, D=1024, H=16, C=3, Dh=64
// q pre-scaled by 0.125*LOG2E; mask in log2e units -> softmax = exp2(st+m).
// Coord bias -cp[k] folded multiplicatively: V rows scaled by e^{-cp[k]} (fp16,
// matched exactly in the denominator via the esch MFMA operand).
#define LOG2E 1.44269504088896f
#define QSCALE 0.18033688011112f   // 0.125 * LOG2E

__device__ __forceinline__ void async16(const void* g, void* l) {
    __builtin_amdgcn_global_load_lds(
        (const __attribute__((address_space(1))) unsigned int*)g,
        (__attribute__((address_space(3))) unsigned int*)l, 16, 0, 0);
}
__device__ __forceinline__ half4 pack4(float a, float b, float c, float d) {
    half2v lo = __builtin_bit_cast(half2v, __builtin_amdgcn_cvt_pkrtz(a, b));
    half2v hi = __builtin_bit_cast(half2v, __builtin_amdgcn_cvt_pkrtz(c, d));
    half4 r; r[0] = lo[0]; r[1] = lo[1]; r[2] = hi[0]; r[3] = hi[1];
    return r;
}
__device__ __forceinline__ half8 cat8(half4 lo, half4 hi) {
    half8 r;
    r[0] = lo[0]; r[1] = lo[1]; r[2] = lo[2]; r[3] = lo[3];
    r[4] = hi[0]; r[5] = hi[1]; r[6] = hi[2]; r[7] = hi[3];
    return r;
}

// ---------------- fused prep: convert_x | transpose_w | escale | prep_mask ----------------
__global__ __launch_bounds__(256) void k_prep(
    const float* __restrict__ x, const float* __restrict__ W,
    const float* __restrict__ coords, const float* __restrict__ rw,
    const float* __restrict__ mask,
    _Float16* __restrict__ xh, _Float16* __restrict__ Wt,
    _Float16* __restrict__ esch, _Float16* __restrict__ maskp) {
    __shared__ float smem[4352];        // 17.4 KB: prep_mask tile 64x68; transpose 32x33
    int bx = blockIdx.x, tid = threadIdx.x;
    if (bx < 2048) {
        // ---- convert x (fp32 -> fp16), 8 elements/thread ----
        int i = bx * 256 + tid;
        const floatx4* xin = (const floatx4*)x;
        floatx4 a = xin[i * 2];
        floatx4 b = xin[i * 2 + 1];
        half8 h;
        h[0] = (_Float16)a[0]; h[1] = (_Float16)a[1]; h[2] = (_Float16)a[2]; h[3] = (_Float16)a[3];
        h[4] = (_Float16)b[0]; h[5] = (_Float16)b[1]; h[6] = (_Float16)b[2]; h[7] = (_Float16)b[3];
        *(half8*)&xh[i * 8] = h;
    } else if (bx < 5120) {
        // ---- transpose + convert Wqkv [1024,3072] -> Wt fp16 [3072,1024] ----
        int b2 = bx - 2048;
        int n0 = (b2 % 96) * 32, k0 = (b2 / 96) * 32;
        int tx = tid & 31, ty = tid >> 5;   // (32,8)
        float (*tile)[33] = (float(*)[33])smem;
        #pragma unroll
        for (int r = 0; r < 4; ++r)
            tile[ty + r * 8][tx] = W[(size_t)(k0 + ty + r * 8) * 3072 + n0 + tx];
        __syncthreads();
        #pragma unroll
        for (int r = 0; r < 4; ++r)
            Wt[(size_t)(n0 + ty + r * 8) * 1024 + k0 + tx] = (_Float16)tile[tx][ty + r * 8];
    } else if (bx < 5376) {
        // ---- esch[b,h,n] = fp16( exp2(-LOG2E * sum_c coords*rw) ) ----
        int idx = (bx - 5120) * 256 + tid;
        int bh = idx >> 11, n = idx & 2047;
        int b = bh >> 4, h = bh & 15;
        const float* c = &coords[(b * 2048 + n) * 3];
        const float* w = &rw[h * 3];
        float v = -LOG2E * (c[0] * w[0] + c[1] * w[1] + c[2] * w[2]);
        esch[idx] = (_Float16)__builtin_amdgcn_exp2f(v);
    } else {
        // ---- mask -> fp16*LOG2E, S^T MFMA C-fragment layout ----
        int bid = bx - 5376;
        int qt = bid >> 5, kt = bid & 31;
        int row0 = qt * 64, col0 = kt * 64;
        int lr = tid >> 2, lc = (tid & 3) * 16;
        #pragma unroll
        for (int j = 0; j < 4; ++j)
            *(floatx4*)&smem[lr * 68 + lc + j * 4] =
                *(const floatx4*)&mask[(size_t)(row0 + lr) * 2048 + col0 + lc + j * 4];
        __syncthreads();
        int w = tid >> 6, lane = tid & 63, quad = lane >> 4, l16 = lane & 15;
        half4* outp = (half4*)maskp + (size_t)((qt * 32 + kt) * 4 + w) * 256 + lane;
        #pragma unroll
        for (int t = 0; t < 4; ++t) {
            floatx4 m = *(const floatx4*)&smem[(w * 16 + l16) * 68 + t * 16 + quad * 4];
            outp[t * 64] = pack4(m[0] * LOG2E, m[1] * LOG2E, m[2] * LOG2E, m[3] * LOG2E);
        }
    }
}

// ---------------- fused QKV GEMM: BK=32, double-buffered async staging ----------------
__global__ __launch_bounds__(256) void k_gemm(
    const _Float16* __restrict__ Ah, const _Float16* __restrict__ Bt,
    const float* __restrict__ bias, const _Float16* __restrict__ esch,
    _Float16* __restrict__ qh, _Float16* __restrict__ kh, _Float16* __restrict__ vt) {
    __shared__ _Float16 smem[16384];   // 2 bufs x (As 4096 + Bs 4096) halves = 32 KB
    int tid = threadIdx.x;
    int w = tid >> 6, lane = tid & 63;
    int quad = lane >> 4, l16 = lane & 15;
    int m0 = blockIdx.y * 128;
    int n0 = blockIdx.x * 128;
    bool QK = n0 < 2048;
    int mq = (w >> 1) * 64, nq = (w & 1) * 64;
    int c0 = n0 + nq;

    int rl4 = lane >> 2;            // row within 16-row staging chunk
    int pb4 = lane & 3;             // physical 16B block within 64B row
    floatx4 acc[4][4] = {};

    const _Float16* ap[2];
    const _Float16* bp[2];
    #pragma unroll
    for (int j = 0; j < 2; ++j) {
        int row = w * 32 + j * 16 + rl4;
        int lb = pb4 ^ (row & 3) ^ ((row >> 2) & 3);
        ap[j] = Ah + (size_t)(m0 + row) * 1024 + lb * 8;
        bp[j] = Bt + (size_t)(n0 + row) * 1024 + lb * 8;
    }

    #define GSTAGE(buf) {                                      \
        _Float16* As_ = smem + (buf) * 8192;                   \
        _Float16* Bs_ = As_ + 4096;                            \
        async16(ap[0], &As_[(w * 32) * 32]);                   \
        async16(ap[1], &As_[(w * 32 + 16) * 32]);              \
        async16(bp[0], &Bs_[(w * 32) * 32]);                   \
        async16(bp[1], &Bs_[(w * 32 + 16) * 32]);              \
        ap[0] += 32; ap[1] += 32; bp[0] += 32; bp[1] += 32;    \
    }

    #define GBODY(cur, last) {                                                         \
        __syncthreads();                                                               \
        if (!(last)) GSTAGE((cur) ^ 1);                                                \
        const _Float16* As_ = smem + (cur) * 8192;                                     \
        const _Float16* Bs_ = As_ + 4096;                                              \
        half8 af[4], bf[4];                                                            \
        _Pragma("unroll")                                                              \
        for (int s = 0; s < 4; ++s) {                                                  \
            int ra = mq + s * 16 + l16;                                                \
            af[s] = *(const half8*)&As_[ra * 32 +                                      \
                ((quad ^ (ra & 3) ^ ((ra >> 2) & 3)) << 3)];                           \
            int rb = nq + s * 16 + l16;                                                \
            bf[s] = *(const half8*)&Bs_[rb * 32 +                                      \
                ((quad ^ (rb & 3) ^ ((rb >> 2) & 3)) << 3)];                           \
        }                                                                              \
        if (QK) {                                                                      \
            _Pragma("unroll")                                                          \
            for (int ms = 0; ms < 4; ++ms)                                             \
                _Pragma("unroll")                                                      \
                for (int ns = 0; ns < 4; ++ns)                                         \
                    acc[ms][ns] = __builtin_amdgcn_mfma_f32_16x16x32_f16(              \
                        bf[ns], af[ms], acc[ms][ns], 0, 0, 0);                         \
        } else {                                                                       \
            _Pragma("unroll")                                                          \
            for (int ms = 0; ms < 4; ++ms)                                             \
                _Pragma("unroll")                                                      \
                for (int ns = 0; ns < 4; ++ns)                                         \
                    acc[ms][ns] = __builtin_amdgcn_mfma_f32_16x16x32_f16(              \
                        af[ms], bf[ns], acc[ms][ns], 0, 0, 0);                         \
        }                                                                              \
    }

    GSTAGE(0);
    #pragma unroll 1
    for (int kt2 = 0; kt2 < 15; ++kt2) {
        GBODY(0, false);
        GBODY(1, false);
    }
    GBODY(0, false);
    GBODY(1, true);
    #undef GBODY
    #undef GSTAGE

    __syncthreads();   // all waves done reading staging before slab reuse

    // ---- epilogue: wave-private 32x72 slab, 2 passes, coalesced half8 stores ----
    _Float16* Ls = smem + w * 2304;
    int rl = lane >> 3, pb = lane & 7;
    int b = (m0 + mq) >> 11, nbase = (m0 + mq) & 2047;
    if (QK) {
        float qsc = (c0 < 1024) ? QSCALE : 1.0f;    // q heads pre-scaled for softmax
        int h2 = c0 >> 6;                           // 0..31: q heads then k heads
        _Float16* dst = (h2 < 16 ? qh : kh) + (size_t)(((b << 4) + (h2 & 15)) * 2048) * 64;
        int d0 = pb << 3;
        #pragma unroll
        for (int p = 0; p < 2; ++p) {
            #pragma unroll
            for (int ns = 0; ns < 4; ++ns) {
                floatx4 b4 = *(const floatx4*)&bias[c0 + ns * 16 + quad * 4];
                #pragma unroll
                for (int m2 = 0; m2 < 2; ++m2) {
                    int ms = p * 2 + m2;
                    floatx4 v;
                    #pragma unroll
                    for (int i = 0; i < 4; ++i) v[i] = (acc[ms][ns][i] + b4[i]) * qsc;
                    *(half4*)&Ls[(m2 * 16 + l16) * 72 + ns * 16 + quad * 4] =
                        pack4(v[0], v[1], v[2], v[3]);
                }
            }
            #pragma unroll
            for (int rep = 0; rep < 4; ++rep) {
                int nl = rep * 8 + rl;
                half8 v = *(const half8*)&Ls[nl * 72 + d0];
                *(half8*)&dst[(size_t)(nbase + p * 32 + nl) * 64 + d0] = v;
            }
        }
    } else {
        int h = (c0 - 2048) >> 6;
        _Float16* dst = vt + (size_t)(((b << 4) + h) * 64) * 2048;
        // V rows scaled by e^{-cp[b,h,n]} in fp32 (single fp16 rounding, matched
        // bit-exactly with the attention denominator which uses the same fp16 esch).
        const _Float16* ePtr = esch + (size_t)((b << 4) + h) * 2048 + nbase + quad * 4;
        float ef[4][4];
        #pragma unroll
        for (int ms = 0; ms < 4; ++ms) {
            half4 e4 = *(const half4*)&ePtr[ms * 16];
            #pragma unroll
            for (int i = 0; i < 4; ++i) ef[ms][i] = (float)e4[i];
        }
        int noff = pb << 3;
        #pragma unroll
        for (int p = 0; p < 2; ++p) {
            #pragma unroll
            for (int n2 = 0; n2 < 2; ++n2) {
                int ns = p * 2 + n2;
                float bv = bias[c0 + ns * 16 + l16];
                #pragma unroll
                for (int ms = 0; ms < 4; ++ms) {
                    *(half4*)&Ls[(n2 * 16 + l16) * 72 + ms * 16 + quad * 4] =
                        pack4((acc[ms][ns][0] + bv) * ef[ms][0],
                              (acc[ms][ns][1] + bv) * ef[ms][1],
                              (acc[ms][ns][2] + bv) * ef[ms][2],
                              (acc[ms][ns][3] + bv) * ef[ms][3]);
                }
            }
            #pragma unroll
            for (int rep = 0; rep < 4; ++rep) {
                int cl = rep * 8 + rl;
                half8 v = *(const half8*)&Ls[cl * 72 + noff];
                *(half8*)&dst[(size_t)(p * 32 + cl) * 2048 + nbase + noff] = v;
            }
        }
    }
}

// ---------------- flash attention: split-K, K-in-registers, XCD-local blocks ----------------
// R10: two changes attacking the 62-us latency wall (R6/R7/R9 fixed occupancy,
// MFMA rate, barrier drain - all counters moved, wall didn't):
// (1) K fragments prefetched GLOBAL->REGISTERS one body ahead (T14). QK starts at
//     the barrier on ready registers: no K ds_read (critical-path LDS latency),
//     no K staging DMA (STAGE 4->2 asyncs), no K swizzle VALU. Each K global load
//     is a coalesced 1KB row-segment; the wq-pair now shares K through L2 not LDS.
//     vmem order per body: [V x2 ... K x4, M x4] -> barrier wait = vmcnt(8)
//     (retires exactly prev V), K/M consumers get compiler auto-waits.
// (2) XCD-bijective block swizzle (T1, 1024%8==0): lbid=(bid&7)*128+(bid>>3) puts
//     all 32 blocks of each bh (4 bh x 512KB = 2MB K/V, fits 4MB L2) on ONE XCD -
//     kills the 8x cross-XCD L2 duplication (FETCH 74MB vs 32MB unique).
// LDS: V dbuf 16KB + es 4KB = 20KB. VGPR budget 128 via waves_per_eu(4,4).
__global__ __launch_bounds__(256) __attribute__((amdgpu_waves_per_eu(4, 4)))
void k_attn(
    const _Float16* __restrict__ qh, const _Float16* __restrict__ kh,
    const _Float16* __restrict__ vt, const _Float16* __restrict__ maskp,
    const _Float16* __restrict__ esch, float* __restrict__ out) {
    __shared__ _Float16 shmem[10240];  // Vs [2][2][2048] (16KB) + es [2048] (4KB)
    _Float16* es = &shmem[8192];
    int tid = threadIdx.x;
    int w = tid >> 6, lane = tid & 63;
    int g2 = w >> 1, wq = w & 1;          // k-group, q-sub-block
    int quad = lane >> 4, l16 = lane & 15;
    int bid = blockIdx.x;
    int lbid = ((bid & 7) << 7) | (bid >> 3);   // XCD-contiguous logical id
    int qt3 = lbid & 31, bh = lbid >> 5;
    int b = bh >> 4, h = bh & 15;
    int qrow = qt3 * 64 + wq * 32;

    // stage esch slice to LDS (visible after the first body's full barrier)
    *(half8*)&es[tid * 8] = *(const half8*)&esch[(size_t)bh * 2048 + tid * 8];

    half8 qf[2][2];
    #pragma unroll
    for (int g = 0; g < 2; ++g) {
        const _Float16* qp = &qh[((size_t)bh * 2048 + qrow + g * 16 + l16) * 64];
        qf[g][0] = *(const half8*)&qp[quad * 8];
        qf[g][1] = *(const half8*)&qp[32 + quad * 8];
    }
    floatx4 o0[4] = {}, o1[4] = {};
    floatx4 ol0 = {}, ol1 = {};        // denominator accumulators (esch-weighted)

    // V staging: [d=64][n=32], packed as 32 super-rows of 128B (d pairs),
    // XOR-swizzled over 8 x 16B slots; wave stages 16 super-rows (2 asyncs of 8)
    int rl = lane >> 3, pb = lane & 7;
    int lbs = pb ^ (rl & 7);                         // logical block at this slot
    const _Float16* vp0 = vt + (size_t)bh * 131072
        + (size_t)(wq * 32 + 2 * rl + (lbs >> 2)) * 2048 + g2 * 1024 + ((lbs & 3) << 3);
    const _Float16* vp1 = vp0 + 16 * 2048;           // +8 super-rows (=16 d rows)
    // K global->register pointer: fragment row l16 (+16 for t=1), 16B chunk quad
    const _Float16* kgp = kh + (size_t)bh * 131072
        + (size_t)(g2 * 1024 + l16) * 64 + quad * 8;
    // mask fragment pointers (as R6): per body advance alternates +128 / +896
    const half4* mp0 = (const half4*)maskp +
        ((size_t)(qt3 * 32 + g2 * 16) * 4 + wq * 2 + 0) * 256 + lane;
    const half4* mp1 = (const half4*)maskp +
        ((size_t)(qt3 * 32 + g2 * 16) * 4 + wq * 2 + 1) * 256 + lane;
    int ecur = g2 * 1024 + quad * 4;      // LDS esch cursor (advances 32/body)

    half4 mC0[2], mC1[2];                 // single-set mask prefetch
    half8 kA0, kA1, kB0, kB1;             // single-set K prefetch (t=0: A, t=1: B)

    #define STAGE(buf) {                                             \
        async16(vp0, &shmem[((g2) * 2 + (buf)) * 2048 + wq * 1024]);       \
        async16(vp1, &shmem[((g2) * 2 + (buf)) * 2048 + wq * 1024 + 512]); \
        vp0 += 32; vp1 += 32;                                        \
    }

    #define KPREF() {                                                \
        kA0 = *(const half8*)kgp;                                    \
        kA1 = *(const half8*)(kgp + 32);                             \
        kB0 = *(const half8*)(kgp + 1024);                           \
        kB1 = *(const half8*)(kgp + 1056);                           \
        kgp += 2048;                                                 \
    }

    #define MPREF(d) {                                               \
        mC0[0] = mp0[0]; mC0[1] = mp0[64];                           \
        mC1[0] = mp1[0]; mC1[1] = mp1[64];                           \
        mp0 += (d); mp1 += (d);                                      \
    }

    #define BODY(cur, last, md, full) {                                                \
        if (full) {                                                                    \
            __syncthreads();                                                           \
        } else {                                                                       \
            asm volatile("s_waitcnt vmcnt(8)" ::: "memory");                           \
            __builtin_amdgcn_s_barrier();                                              \
        }                                                                              \
        __builtin_amdgcn_sched_barrier(0);  /* nothing crosses the barrier */          \
        if (!(last)) STAGE((cur) ^ 1);                                                 \
        __builtin_amdgcn_sched_barrier(0);  /* V-stage issues before all else */       \
        const _Float16* Vsc = &shmem[((g2) * 2 + (cur)) * 2048];                       \
        half4 ptl[2][2];                                                               \
        {   /* t = 0 : K regs kA0/kA1 */                                               \
            half4 ml = mC0[0];                                                         \
            floatx4 z;                                                                 \
            z[0] = (float)ml[0]; z[1] = (float)ml[1];                                  \
            z[2] = (float)ml[2]; z[3] = (float)ml[3];                                  \
            z = __builtin_amdgcn_mfma_f32_16x16x32_f16(kA0, qf[0][0], z, 0, 0, 0);     \
            z = __builtin_amdgcn_mfma_f32_16x16x32_f16(kA1, qf[0][1], z, 0, 0, 0);     \
            ptl[0][0] = pack4(__builtin_amdgcn_exp2f(z[0]),                            \
                              __builtin_amdgcn_exp2f(z[1]),                            \
                              __builtin_amdgcn_exp2f(z[2]),                            \
                              __builtin_amdgcn_exp2f(z[3]));                           \
            ml = mC1[0];                                                               \
            z[0] = (float)ml[0]; z[1] = (float)ml[1];                                  \
            z[2] = (float)ml[2]; z[3] = (float)ml[3];                                  \
            z = __builtin_amdgcn_mfma_f32_16x16x32_f16(kA0, qf[1][0], z, 0, 0, 0);     \
            z = __builtin_amdgcn_mfma_f32_16x16x32_f16(kA1, qf[1][1], z, 0, 0, 0);     \
            ptl[1][0] = pack4(__builtin_amdgcn_exp2f(z[0]),                            \
                              __builtin_amdgcn_exp2f(z[1]),                            \
                              __builtin_amdgcn_exp2f(z[2]),                            \
                              __builtin_amdgcn_exp2f(z[3]));                           \
        }                                                                              \
        {   /* t = 1 : K regs kB0/kB1 */                                               \
            half4 ml = mC0[1];                                                         \
            floatx4 z;                                                                 \
            z[0] = (float)ml[0]; z[1] = (float)ml[1];                                  \
            z[2] = (float)ml[2]; z[3] = (float)ml[3];                                  \
            z = __builtin_amdgcn_mfma_f32_16x16x32_f16(kB0, qf[0][0], z, 0, 0, 0);     \
            z = __builtin_amdgcn_mfma_f32_16x16x32_f16(kB1, qf[0][1], z, 0, 0, 0);     \
            ptl[0][1] = pack4(__builtin_amdgcn_exp2f(z[0]),                            \
                              __builtin_amdgcn_exp2f(z[1]),                            \
                              __builtin_amdgcn_exp2f(z[2]),                            \
                              __builtin_amdgcn_exp2f(z[3]));                           \
            ml = mC1[1];                                                               \
            z[0] = (float)ml[0]; z[1] = (float)ml[1];                                  \
            z[2] = (float)ml[2]; z[3] = (float)ml[3];                                  \
            z = __builtin_amdgcn_mfma_f32_16x16x32_f16(kB0, qf[1][0], z, 0, 0, 0);     \
            z = __builtin_amdgcn_mfma_f32_16x16x32_f16(kB1, qf[1][1], z, 0, 0, 0);     \
            ptl[1][1] = pack4(__builtin_amdgcn_exp2f(z[0]),                            \
                              __builtin_amdgcn_exp2f(z[1]),                            \
                              __builtin_amdgcn_exp2f(z[2]),                            \
                              __builtin_amdgcn_exp2f(z[3]));                           \
        }                                                                              \
        if (!(last)) { KPREF(); MPREF(md); }  /* issue next body's K+mask (WAR-safe) */ \
        half8 pt8_0 = cat8(ptl[0][0], ptl[0][1]);                                      \
        half8 pt8_1 = cat8(ptl[1][0], ptl[1][1]);                                      \
        {                                                                              \
            half4 e0 = *(const half4*)&es[ecur];                                       \
            half4 e1 = *(const half4*)&es[ecur + 16];                                  \
            half8 ev = cat8(e0, e1);                                                   \
            ol0 = __builtin_amdgcn_mfma_f32_16x16x32_f16(ev, pt8_0, ol0, 0, 0, 0);     \
            ol1 = __builtin_amdgcn_mfma_f32_16x16x32_f16(ev, pt8_1, ol1, 0, 0, 0);     \
        }                                                                              \
        ecur += 32;                                                                    \
        _Pragma("unroll")                                                              \
        for (int dt = 0; dt < 4; ++dt) {                                               \
            int rv = dt * 16 + l16;                                                    \
            int sr = rv >> 1;                                                          \
            int lb0 = ((rv & 1) << 2) | (quad >> 1);                                   \
            half4 vlo = *(const half4*)&Vsc[sr * 64 +                                  \
                ((lb0 ^ (sr & 7)) << 3) + ((quad & 1) << 2)];                          \
            half4 vhi = *(const half4*)&Vsc[sr * 64 +                                  \
                (((lb0 | 2) ^ (sr & 7)) << 3) + ((quad & 1) << 2)];                    \
            half8 vf = cat8(vlo, vhi);                                                 \
            o0[dt] = __builtin_amdgcn_mfma_f32_16x16x32_f16(vf, pt8_0, o0[dt], 0, 0, 0); \
            o1[dt] = __builtin_amdgcn_mfma_f32_16x16x32_f16(vf, pt8_1, o1[dt], 0, 0, 0); \
        }                                                                              \
    }

    STAGE(0);
    KPREF();
    MPREF(128);
    BODY(0, false, 896, 1);   // first body: full sync (drains es ds_write + all loads)
    BODY(1, false, 128, 0);
    #pragma unroll 1
    for (int kt2 = 0; kt2 < 14; ++kt2) {
        BODY(0, false, 896, 0);
        BODY(1, false, 128, 0);
    }
    BODY(0, false, 896, 0);
    BODY(1, true, 0, 0);
    #undef BODY
    #undef MPREF
    #undef KPREF
    #undef STAGE

    // ---- combine partials across the wave pair (w, w^2) via LDS ----
    __syncthreads();                       // full drain: everyone done reading staging
    float* comb = (float*)shmem;           // 4 waves x 17 idx x 64 lanes = 17.4 KB <= 20 KB
    {
        float* dst = comb + ((size_t)w * 17) * 64 + lane;
        if (g2 == 0) {                     // group 0 exports o1/ol1
            #pragma unroll
            for (int dt = 0; dt < 4; ++dt)
                #pragma unroll
                for (int i = 0; i < 4; ++i)
                    dst[(dt * 4 + i) * 64] = o1[dt][i];
            dst[16 * 64] = ol1[0];
        } else {                           // group 1 exports o0/ol0
            #pragma unroll
            for (int dt = 0; dt < 4; ++dt)
                #pragma unroll
                for (int i = 0; i < 4; ++i)
                    dst[(dt * 4 + i) * 64] = o0[dt][i];
            dst[16 * 64] = ol0[0];
        }
    }
    __syncthreads();
    {
        const float* src = comb + ((size_t)(w ^ 2) * 17) * 64 + lane;
        if (g2 == 0) {
            // sum own o0 with partner's o0 -> store q-group 0 (rows qrow + l16)
            #pragma unroll
            for (int dt = 0; dt < 4; ++dt)
                #pragma unroll
                for (int i = 0; i < 4; ++i)
                    o0[dt][i] += src[(dt * 4 + i) * 64];
            float inv = 1.f / (ol0[0] + src[16 * 64]);
            size_t obase = ((size_t)(b * 2048 + qrow + l16)) * 1024 + h * 64 + quad * 4;
            #pragma unroll
            for (int dt = 0; dt < 4; ++dt) {
                floatx4 r;
                #pragma unroll
                for (int i = 0; i < 4; ++i) r[i] = o0[dt][i] * inv;
                *(floatx4*)&out[obase + dt * 16] = r;
            }
        } else {
            // sum own o1 with partner's o1 -> store q-group 1 (rows qrow + 16 + l16)
            #pragma unroll
            for (int dt = 0; dt < 4; ++dt)
                #pragma unroll
                for (int i = 0; i < 4; ++i)
                    o1[dt][i] += src[(dt * 4 + i) * 64];
            float inv = 1.f / (ol1[0] + src[16 * 64]);
            size_t obase = ((size_t)(b * 2048 + qrow + 16 + l16)) * 1024 + h * 64 + quad * 4;
            #pragma unroll
            for (int dt = 0; dt < 4; ++dt) {
                floatx4 r;
                #pragma unroll
                for (int i = 0; i < 4; ++i) r[i] = o1[dt][i] * inv;
                *(floatx4*)&out[obase + dt * 16] = r;
            }
        }
    }
}

extern "C" void kernel_launch(void* const* d_in, const int* in_sizes, int n_in,
                              void* d_out, int out_size, void* d_ws, size_t ws_size,
                              hipStream_t stream) {
    const float* x      = (const float*)d_in[0];
    const float* coords = (const float*)d_in[1];
    const float* mask   = (const float*)d_in[2];
    const float* Wqkv   = (const float*)d_in[3];
    const float* bqkv   = (const float*)d_in[4];
    const float* rw     = (const float*)d_in[5];
    float* out = (float*)d_out;

    // Workspace layout
    //   xh   : [0,          8,388,608)
    //   maskp: [8,388,608,  16,777,216)
    //   Wt   : [16,777,216, 23,068,672)
    //   qh   : [23,068,672, 31,457,280)
    //   kh   : [31,457,280, 39,845,888)
    //   vt   : [39,845,888, 48,234,496)
    //   esch : [48,234,496, 48,365,568)
    char* ws = (char*)d_ws;
    _Float16* xh    = (_Float16*)(ws);
    _Float16* maskp = (_Float16*)(ws + 8388608);
    _Float16* Wt    = (_Float16*)(ws + 16777216);
    _Float16* qh    = (_Float16*)(ws + 23068672);
    _Float16* kh    = (_Float16*)(ws + 31457280);
    _Float16* vt    = (_Float16*)(ws + 39845888);
    _Float16* esch  = (_Float16*)(ws + 48234496);

    k_prep<<<6400, 256, 0, stream>>>(x, Wqkv, coords, rw, mask, xh, Wt, esch, maskp);
    k_gemm<<<dim3(24, 32), 256, 0, stream>>>(xh, Wt, bqkv, esch, qh, kh, vt);
    k_attn<<<1024, 256, 0, stream>>>(qh, kh, vt, maskp, esch, out);
}

// Round 11
// 182.630 us; speedup vs baseline: 1.2193x; 1.2193x over previous
//
#include <hip/hip_runtime.h>

typedef _Float16 half8 __attribute__((ext_vector_type(8)));
typedef _Float16 half4 __attribute__((ext_vector_type(4)));
typedef _Float16 half2v __attribute__((ext_vector_type(2)));
typedef float floatx4 __attribute__((ext_vector_type(4)));

// Problem constants: B=2, N=2048, D=1024, H=16, C=3, Dh=64
// q pre-scaled by 0.125*LOG2E; mask in log2e units -> softmax = exp2(st+m).
// Coord bias -cp[k] folded multiplicatively: V rows scaled by e^{-cp[k]} (fp16,
// matched exactly in the denominator via the esch MFMA operand).
#define LOG2E 1.44269504088896f
#define QSCALE 0.18033688011112f   // 0.125 * LOG2E

__device__ __forceinline__ void async16(const void* g, void* l) {
    __builtin_amdgcn_global_load_lds(
        (const __attribute__((address_space(1))) unsigned int*)g,
        (__attribute__((address_space(3))) unsigned int*)l, 16, 0, 0);
}
__device__ __forceinline__ half4 pack4(float a, float b, float c, float d) {
    half2v lo = __builtin_bit_cast(half2v, __builtin_amdgcn_cvt_pkrtz(a, b));
    half2v hi = __builtin_bit_cast(half2v, __builtin_amdgcn_cvt_pkrtz(c, d));
    half4 r; r[0] = lo[0]; r[1] = lo[1]; r[2] = hi[0]; r[3] = hi[1];
    return r;
}
__device__ __forceinline__ half8 cat8(half4 lo, half4 hi) {
    half8 r;
    r[0] = lo[0]; r[1] = lo[1]; r[2] = lo[2]; r[3] = lo[3];
    r[4] = hi[0]; r[5] = hi[1]; r[6] = hi[2]; r[7] = hi[3];
    return r;
}

// ---------------- fused prep: convert_x | transpose_w | escale | prep_mask ----------------
__global__ __launch_bounds__(256) void k_prep(
    const float* __restrict__ x, const float* __restrict__ W,
    const float* __restrict__ coords, const float* __restrict__ rw,
    const float* __restrict__ mask,
    _Float16* __restrict__ xh, _Float16* __restrict__ Wt,
    _Float16* __restrict__ esch, _Float16* __restrict__ maskp) {
    __shared__ float smem[4352];        // 17.4 KB: prep_mask tile 64x68; transpose 32x33
    int bx = blockIdx.x, tid = threadIdx.x;
    if (bx < 2048) {
        // ---- convert x (fp32 -> fp16), 8 elements/thread ----
        int i = bx * 256 + tid;
        const floatx4* xin = (const floatx4*)x;
        floatx4 a = xin[i * 2];
        floatx4 b = xin[i * 2 + 1];
        half8 h;
        h[0] = (_Float16)a[0]; h[1] = (_Float16)a[1]; h[2] = (_Float16)a[2]; h[3] = (_Float16)a[3];
        h[4] = (_Float16)b[0]; h[5] = (_Float16)b[1]; h[6] = (_Float16)b[2]; h[7] = (_Float16)b[3];
        *(half8*)&xh[i * 8] = h;
    } else if (bx < 5120) {
        // ---- transpose + convert Wqkv [1024,3072] -> Wt fp16 [3072,1024] ----
        int b2 = bx - 2048;
        int n0 = (b2 % 96) * 32, k0 = (b2 / 96) * 32;
        int tx = tid & 31, ty = tid >> 5;   // (32,8)
        float (*tile)[33] = (float(*)[33])smem;
        #pragma unroll
        for (int r = 0; r < 4; ++r)
            tile[ty + r * 8][tx] = W[(size_t)(k0 + ty + r * 8) * 3072 + n0 + tx];
        __syncthreads();
        #pragma unroll
        for (int r = 0; r < 4; ++r)
            Wt[(size_t)(n0 + ty + r * 8) * 1024 + k0 + tx] = (_Float16)tile[tx][ty + r * 8];
    } else if (bx < 5376) {
        // ---- esch[b,h,n] = fp16( exp2(-LOG2E * sum_c coords*rw) ) ----
        int idx = (bx - 5120) * 256 + tid;
        int bh = idx >> 11, n = idx & 2047;
        int b = bh >> 4, h = bh & 15;
        const float* c = &coords[(b * 2048 + n) * 3];
        const float* w = &rw[h * 3];
        float v = -LOG2E * (c[0] * w[0] + c[1] * w[1] + c[2] * w[2]);
        esch[idx] = (_Float16)__builtin_amdgcn_exp2f(v);
    } else {
        // ---- mask -> fp16*LOG2E, S^T MFMA C-fragment layout ----
        int bid = bx - 5376;
        int qt = bid >> 5, kt = bid & 31;
        int row0 = qt * 64, col0 = kt * 64;
        int lr = tid >> 2, lc = (tid & 3) * 16;
        #pragma unroll
        for (int j = 0; j < 4; ++j)
            *(floatx4*)&smem[lr * 68 + lc + j * 4] =
                *(const floatx4*)&mask[(size_t)(row0 + lr) * 2048 + col0 + lc + j * 4];
        __syncthreads();
        int w = tid >> 6, lane = tid & 63, quad = lane >> 4, l16 = lane & 15;
        half4* outp = (half4*)maskp + (size_t)((qt * 32 + kt) * 4 + w) * 256 + lane;
        #pragma unroll
        for (int t = 0; t < 4; ++t) {
            floatx4 m = *(const floatx4*)&smem[(w * 16 + l16) * 68 + t * 16 + quad * 4];
            outp[t * 64] = pack4(m[0] * LOG2E, m[1] * LOG2E, m[2] * LOG2E, m[3] * LOG2E);
        }
    }
}

// ---------------- fused QKV GEMM: BK=64 (m97 config), double-buffered async staging ----------------
// R11: BK 32 -> 64. Halves barrier count (32 -> 16 bodies), doubles staging depth
// (8 asyncs in flight), 32 MFMA/body amortizing each barrier over 2x compute --
// the guide's m97-proven 128%/BK=64 config (874-912 TF ref-checked). LDS 64 KB ->
// 2 blocks/CU (m97's occupancy). Frags consumed in two k-half passes to keep live
// registers at the old (spill-free) level. 8-chunk XOR swizzle (chunk ^ row&7):
// ds_read_b128 2-way (free); staging source pre-swizzled to match.
__global__ __launch_bounds__(256) void k_gemm(
    const _Float16* __restrict__ Ah, const _Float16* __restrict__ Bt,
    const float* __restrict__ bias, const _Float16* __restrict__ esch,
    _Float16* __restrict__ qh, _Float16* __restrict__ kh, _Float16* __restrict__ vt) {
    __shared__ _Float16 smem[32768];   // 2 bufs x (As 8192 + Bs 8192) halves = 64 KB
    int tid = threadIdx.x;
    int w = tid >> 6, lane = tid & 63;
    int quad = lane >> 4, l16 = lane & 15;
    int m0 = blockIdx.y * 128;
    int n0 = blockIdx.x * 128;
    bool QK = n0 < 2048;
    int mq = (w >> 1) * 64, nq = (w & 1) * 64;
    int c0 = n0 + nq;

    int rl8 = lane >> 3;            // row within 8-row staging chunk
    int pb8 = lane & 7;             // physical 16B block within 128B row
    floatx4 acc[4][4] = {};

    const _Float16* ap[4];
    const _Float16* bp[4];
    #pragma unroll
    for (int j = 0; j < 4; ++j) {
        int row = w * 32 + j * 8 + rl8;
        int lb = pb8 ^ (row & 7);
        ap[j] = Ah + (size_t)(m0 + row) * 1024 + lb * 8;
        bp[j] = Bt + (size_t)(n0 + row) * 1024 + lb * 8;
    }

    #define GSTAGE(buf) {                                      \
        _Float16* As_ = smem + (buf) * 16384;                  \
        _Float16* Bs_ = As_ + 8192;                            \
        _Pragma("unroll")                                      \
        for (int j = 0; j < 4; ++j) {                          \
            async16(ap[j], &As_[(w * 32 + j * 8) * 64]);       \
            ap[j] += 64;                                       \
        }                                                      \
        _Pragma("unroll")                                      \
        for (int j = 0; j < 4; ++j) {                          \
            async16(bp[j], &Bs_[(w * 32 + j * 8) * 64]);       \
            bp[j] += 64;                                       \
        }                                                      \
    }

    #define GHALF(As_, Bs_, cblk) {                                                   \
        half8 af[4], bf[4];                                                            \
        _Pragma("unroll")                                                              \
        for (int s = 0; s < 4; ++s) {                                                  \
            int ra = mq + s * 16 + l16;                                                \
            af[s] = *(const half8*)&As_[ra * 64 + ((((cblk) | quad) ^ (ra & 7)) << 3)]; \
            int rb = nq + s * 16 + l16;                                                \
            bf[s] = *(const half8*)&Bs_[rb * 64 + ((((cblk) | quad) ^ (rb & 7)) << 3)]; \
        }                                                                              \
        if (QK) {                                                                      \
            _Pragma("unroll")                                                          \
            for (int ms = 0; ms < 4; ++ms)                                             \
                _Pragma("unroll")                                                      \
                for (int ns = 0; ns < 4; ++ns)                                         \
                    acc[ms][ns] = __builtin_amdgcn_mfma_f32_16x16x32_f16(              \
                        bf[ns], af[ms], acc[ms][ns], 0, 0, 0);                         \
        } else {                                                                       \
            _Pragma("unroll")                                                          \
            for (int ms = 0; ms < 4; ++ms)                                             \
                _Pragma("unroll")                                                      \
                for (int ns = 0; ns < 4; ++ns)                                         \
                    acc[ms][ns] = __builtin_amdgcn_mfma_f32_16x16x32_f16(              \
                        af[ms], bf[ns], acc[ms][ns], 0, 0, 0);                         \
        }                                                                              \
    }

    #define GBODY(cur, last) {                                                         \
        __syncthreads();                                                               \
        if (!(last)) GSTAGE((cur) ^ 1);                                                \
        const _Float16* As_ = smem + (cur) * 16384;                                    \
        const _Float16* Bs_ = As_ + 8192;                                              \
        GHALF(As_, Bs_, 0);                                                            \
        GHALF(As_, Bs_, 4);                                                            \
    }

    GSTAGE(0);
    #pragma unroll 1
    for (int kt2 = 0; kt2 < 7; ++kt2) {
        GBODY(0, false);
        GBODY(1, false);
    }
    GBODY(0, false);
    GBODY(1, true);
    #undef GBODY
    #undef GHALF
    #undef GSTAGE

    __syncthreads();   // all waves done reading staging before slab reuse

    // ---- epilogue: wave-private 32x72 slab, 2 passes, coalesced half8 stores ----
    _Float16* Ls = smem + w * 2304;
    int rl = lane >> 3, pb = lane & 7;
    int b = (m0 + mq) >> 11, nbase = (m0 + mq) & 2047;
    if (QK) {
        float qsc = (c0 < 1024) ? QSCALE : 1.0f;    // q heads pre-scaled for softmax
        int h2 = c0 >> 6;                           // 0..31: q heads then k heads
        _Float16* dst = (h2 < 16 ? qh : kh) + (size_t)(((b << 4) + (h2 & 15)) * 2048) * 64;
        int d0 = pb << 3;
        #pragma unroll
        for (int p = 0; p < 2; ++p) {
            #pragma unroll
            for (int ns = 0; ns < 4; ++ns) {
                floatx4 b4 = *(const floatx4*)&bias[c0 + ns * 16 + quad * 4];
                #pragma unroll
                for (int m2 = 0; m2 < 2; ++m2) {
                    int ms = p * 2 + m2;
                    floatx4 v;
                    #pragma unroll
                    for (int i = 0; i < 4; ++i) v[i] = (acc[ms][ns][i] + b4[i]) * qsc;
                    *(half4*)&Ls[(m2 * 16 + l16) * 72 + ns * 16 + quad * 4] =
                        pack4(v[0], v[1], v[2], v[3]);
                }
            }
            #pragma unroll
            for (int rep = 0; rep < 4; ++rep) {
                int nl = rep * 8 + rl;
                half8 v = *(const half8*)&Ls[nl * 72 + d0];
                *(half8*)&dst[(size_t)(nbase + p * 32 + nl) * 64 + d0] = v;
            }
        }
    } else {
        int h = (c0 - 2048) >> 6;
        _Float16* dst = vt + (size_t)(((b << 4) + h) * 64) * 2048;
        // V rows scaled by e^{-cp[b,h,n]} in fp32 (single fp16 rounding, matched
        // bit-exactly with the attention denominator which uses the same fp16 esch).
        const _Float16* ePtr = esch + (size_t)((b << 4) + h) * 2048 + nbase + quad * 4;
        float ef[4][4];
        #pragma unroll
        for (int ms = 0; ms < 4; ++ms) {
            half4 e4 = *(const half4*)&ePtr[ms * 16];
            #pragma unroll
            for (int i = 0; i < 4; ++i) ef[ms][i] = (float)e4[i];
        }
        int noff = pb << 3;
        #pragma unroll
        for (int p = 0; p < 2; ++p) {
            #pragma unroll
            for (int n2 = 0; n2 < 2; ++n2) {
                int ns = p * 2 + n2;
                float bv = bias[c0 + ns * 16 + l16];
                #pragma unroll
                for (int ms = 0; ms < 4; ++ms) {
                    *(half4*)&Ls[(n2 * 16 + l16) * 72 + ms * 16 + quad * 4] =
                        pack4((acc[ms][ns][0] + bv) * ef[ms][0],
                              (acc[ms][ns][1] + bv) * ef[ms][1],
                              (acc[ms][ns][2] + bv) * ef[ms][2],
                              (acc[ms][ns][3] + bv) * ef[ms][3]);
                }
            }
            #pragma unroll
            for (int rep = 0; rep < 4; ++rep) {
                int cl = rep * 8 + rl;
                half8 v = *(const half8*)&Ls[cl * 72 + noff];
                *(half8*)&dst[(size_t)(p * 32 + cl) * 2048 + nbase + noff] = v;
            }
        }
    }
}

// ---------------- flash attention: split-K, 256 thr, KVBLK=32, counted-vmcnt barriers ----------------
// R11 = exact revert to R9's k_attn (62 us, passing; R10's K-in-reg + XCD swizzle
// regressed to 99 us: 2x redundant K global traffic, FETCH 74->105 MB).
// Counted-vmcnt scheme + sched_barrier(0) fences pinning vmem issue order:
// vmcnt(4) at the barrier retires exactly the previous body's 4 STAGE loads;
// mask register loads fly across the barrier.
__global__ __launch_bounds__(256) __attribute__((amdgpu_waves_per_eu(4, 4)))
void k_attn(
    const _Float16* __restrict__ qh, const _Float16* __restrict__ kh,
    const _Float16* __restrict__ vt, const _Float16* __restrict__ maskp,
    const _Float16* __restrict__ esch, float* __restrict__ out) {
    __shared__ _Float16 KV[2][2][4096];   // [group][buf]: K [0,2048), V [2048,4096); 32 KB
    __shared__ _Float16 es[2048];         // esch slice for this bh (4 KB)
    int tid = threadIdx.x;
    int w = tid >> 6, lane = tid & 63;
    int g2 = w >> 1, wq = w & 1;          // k-group, q-sub-block
    int quad = lane >> 4, l16 = lane & 15;
    int bid = blockIdx.x;
    int qt3 = bid & 31, bh = bid >> 5;
    int b = bh >> 4, h = bh & 15;
    int qrow = qt3 * 64 + wq * 32;

    // stage esch slice to LDS (visible after the first body's full barrier)
    *(half8*)&es[tid * 8] = *(const half8*)&esch[(size_t)bh * 2048 + tid * 8];

    half8 qf[2][2];
    #pragma unroll
    for (int g = 0; g < 2; ++g) {
        const _Float16* qp = &qh[((size_t)bh * 2048 + qrow + g * 16 + l16) * 64];
        qf[g][0] = *(const half8*)&qp[quad * 8];
        qf[g][1] = *(const half8*)&qp[32 + quad * 8];
    }
    floatx4 o0[4] = {}, o1[4] = {};
    floatx4 ol0 = {}, ol1 = {};        // denominator accumulators (esch-weighted)

    // K staging: 32 rows x 64 cols per tile; wave stages 16 rows (2 asyncs of 8)
    int rl = lane >> 3, pb = lane & 7;
    int swk = (pb ^ rl) << 3;
    const _Float16* kp0 = kh + (size_t)bh * 131072
        + (size_t)(g2 * 1024 + wq * 16 + rl) * 64 + swk;
    const _Float16* kp1 = kp0 + 512;                 // +8 k rows
    // V staging: [d=64][n=32], packed as 32 super-rows of 128B (d pairs),
    // XOR-swizzled over 8 x 16B slots; wave stages 16 super-rows (2 asyncs of 8)
    int lbs = pb ^ (rl & 7);                         // logical block at this slot
    const _Float16* vp0 = vt + (size_t)bh * 131072
        + (size_t)(wq * 32 + 2 * rl + (lbs >> 2)) * 2048 + g2 * 1024 + ((lbs & 3) << 3);
    const _Float16* vp1 = vp0 + 16 * 2048;           // +8 super-rows (=16 d rows)
    // mask fragment pointers: frag block = ((qt3*32 + kt_old)*4 + w16)*256 + lane,
    // w16 = wq*2 + g; per body (32 k cols) advance alternates +128 / +896
    const half4* mp0 = (const half4*)maskp +
        ((size_t)(qt3 * 32 + g2 * 16) * 4 + wq * 2 + 0) * 256 + lane;
    const half4* mp1 = (const half4*)maskp +
        ((size_t)(qt3 * 32 + g2 * 16) * 4 + wq * 2 + 1) * 256 + lane;
    int ecur = g2 * 1024 + quad * 4;      // LDS esch cursor (advances 32/body)

    half4 mC0[2], mC1[2];                 // single-set mask prefetch (2 frags/group)

    #define STAGE(buf) {                                             \
        async16(kp0, &KV[g2][buf][wq * 1024]);                       \
        async16(kp1, &KV[g2][buf][wq * 1024 + 512]);                 \
        async16(vp0, &KV[g2][buf][2048 + wq * 1024]);                \
        async16(vp1, &KV[g2][buf][2048 + wq * 1024 + 512]);          \
        kp0 += 2048; kp1 += 2048; vp0 += 32; vp1 += 32;              \
    }

    #define MPREF(d) {                                               \
        mC0[0] = mp0[0]; mC0[1] = mp0[64];                           \
        mC1[0] = mp1[0]; mC1[1] = mp1[64];                           \
        mp0 += (d); mp1 += (d);                                      \
    }

    #define BODY(cur, last, md, full) {                                                \
        if (full) {                                                                    \
            __syncthreads();                                                           \
        } else {                                                                       \
            asm volatile("s_waitcnt vmcnt(4)" ::: "memory");                           \
            __builtin_amdgcn_s_barrier();                                              \
        }                                                                              \
        __builtin_amdgcn_sched_barrier(0);  /* nothing crosses the barrier */          \
        if (!(last)) STAGE((cur) ^ 1);                                                 \
        __builtin_amdgcn_sched_barrier(0);  /* STAGE loads issue before all else */    \
        const _Float16* Ksc = &KV[g2][cur][0];                                         \
        const _Float16* Vsc = &KV[g2][cur][2048];                                      \
        half4 ptl[2][2];                                                               \
        _Pragma("unroll")                                                              \
        for (int t = 0; t < 2; ++t) {                                                  \
            int r = t * 16 + l16;                                                      \
            half8 k0 = *(const half8*)&Ksc[r * 64 + ((quad ^ (r & 7)) << 3)];          \
            half8 k1 = *(const half8*)&Ksc[r * 64 + (((quad + 4) ^ (r & 7)) << 3)];    \
            {                                                                          \
                half4 ml = mC0[t];                                                     \
                floatx4 z;                                                             \
                z[0] = (float)ml[0]; z[1] = (float)ml[1];                              \
                z[2] = (float)ml[2]; z[3] = (float)ml[3];                              \
                z = __builtin_amdgcn_mfma_f32_16x16x32_f16(k0, qf[0][0], z, 0, 0, 0);  \
                z = __builtin_amdgcn_mfma_f32_16x16x32_f16(k1, qf[0][1], z, 0, 0, 0);  \
                ptl[0][t] = pack4(__builtin_amdgcn_exp2f(z[0]),                        \
                                  __builtin_amdgcn_exp2f(z[1]),                        \
                                  __builtin_amdgcn_exp2f(z[2]),                        \
                                  __builtin_amdgcn_exp2f(z[3]));                       \
            }                                                                          \
            {                                                                          \
                half4 ml = mC1[t];                                                     \
                floatx4 z;                                                             \
                z[0] = (float)ml[0]; z[1] = (float)ml[1];                              \
                z[2] = (float)ml[2]; z[3] = (float)ml[3];                              \
                z = __builtin_amdgcn_mfma_f32_16x16x32_f16(k0, qf[1][0], z, 0, 0, 0);  \
                z = __builtin_amdgcn_mfma_f32_16x16x32_f16(k1, qf[1][1], z, 0, 0, 0);  \
                ptl[1][t] = pack4(__builtin_amdgcn_exp2f(z[0]),                        \
                                  __builtin_amdgcn_exp2f(z[1]),                        \
                                  __builtin_amdgcn_exp2f(z[2]),                        \
                                  __builtin_amdgcn_exp2f(z[3]));                       \
            }                                                                          \
        }                                                                              \
        if (!(last)) MPREF(md);                                                        \
        half8 pt8_0 = cat8(ptl[0][0], ptl[0][1]);                                      \
        half8 pt8_1 = cat8(ptl[1][0], ptl[1][1]);                                      \
        {                                                                              \
            half4 e0 = *(const half4*)&es[ecur];                                       \
            half4 e1 = *(const half4*)&es[ecur + 16];                                  \
            half8 ev = cat8(e0, e1);                                                   \
            ol0 = __builtin_amdgcn_mfma_f32_16x16x32_f16(ev, pt8_0, ol0, 0, 0, 0);     \
            ol1 = __builtin_amdgcn_mfma_f32_16x16x32_f16(ev, pt8_1, ol1, 0, 0, 0);     \
        }                                                                              \
        ecur += 32;                                                                    \
        _Pragma("unroll")                                                              \
        for (int dt = 0; dt < 4; ++dt) {                                               \
            int rv = dt * 16 + l16;                                                    \
            int sr = rv >> 1;                                                          \
            int lb0 = ((rv & 1) << 2) | (quad >> 1);                                   \
            half4 vlo = *(const half4*)&Vsc[sr * 64 +                                  \
                ((lb0 ^ (sr & 7)) << 3) + ((quad & 1) << 2)];                          \
            half4 vhi = *(const half4*)&Vsc[sr * 64 +                                  \
                (((lb0 | 2) ^ (sr & 7)) << 3) + ((quad & 1) << 2)];                    \
            half8 vf = cat8(vlo, vhi);                                                 \
            o0[dt] = __builtin_amdgcn_mfma_f32_16x16x32_f16(vf, pt8_0, o0[dt], 0, 0, 0); \
            o1[dt] = __builtin_amdgcn_mfma_f32_16x16x32_f16(vf, pt8_1, o1[dt], 0, 0, 0); \
        }                                                                              \
    }

    STAGE(0);
    MPREF(128);
    BODY(0, false, 896, 1);   // first body: full sync (drains es ds_write + q loads)
    BODY(1, false, 128, 0);
    #pragma unroll 1
    for (int kt2 = 0; kt2 < 14; ++kt2) {
        BODY(0, false, 896, 0);
        BODY(1, false, 128, 0);
    }
    BODY(0, false, 896, 0);
    BODY(1, true, 0, 0);
    #undef BODY
    #undef MPREF
    #undef STAGE

    // ---- combine partials across the wave pair (w, w^2) via LDS ----
    __syncthreads();                       // full drain: everyone done reading staging
    float* comb = (float*)KV;              // 4 waves x 17 idx x 64 lanes = 17.4 KB
    {
        float* dst = comb + ((size_t)w * 17) * 64 + lane;
        if (g2 == 0) {                     // group 0 exports o1/ol1
            #pragma unroll
            for (int dt = 0; dt < 4; ++dt)
                #pragma unroll
                for (int i = 0; i < 4; ++i)
                    dst[(dt * 4 + i) * 64] = o1[dt][i];
            dst[16 * 64] = ol1[0];
        } else {                           // group 1 exports o0/ol0
            #pragma unroll
            for (int dt = 0; dt < 4; ++dt)
                #pragma unroll
                for (int i = 0; i < 4; ++i)
                    dst[(dt * 4 + i) * 64] = o0[dt][i];
            dst[16 * 64] = ol0[0];
        }
    }
    __syncthreads();
    {
        const float* src = comb + ((size_t)(w ^ 2) * 17) * 64 + lane;
        if (g2 == 0) {
            // sum own o0 with partner's o0 -> store q-group 0 (rows qrow + l16)
            #pragma unroll
            for (int dt = 0; dt < 4; ++dt)
                #pragma unroll
                for (int i = 0; i < 4; ++i)
                    o0[dt][i] += src[(dt * 4 + i) * 64];
            float inv = 1.f / (ol0[0] + src[16 * 64]);
            size_t obase = ((size_t)(b * 2048 + qrow + l16)) * 1024 + h * 64 + quad * 4;
            #pragma unroll
            for (int dt = 0; dt < 4; ++dt) {
                floatx4 r;
                #pragma unroll
                for (int i = 0; i < 4; ++i) r[i] = o0[dt][i] * inv;
                *(floatx4*)&out[obase + dt * 16] = r;
            }
        } else {
            // sum own o1 with partner's o1 -> store q-group 1 (rows qrow + 16 + l16)
            #pragma unroll
            for (int dt = 0; dt < 4; ++dt)
                #pragma unroll
                for (int i = 0; i < 4; ++i)
                    o1[dt][i] += src[(dt * 4 + i) * 64];
            float inv = 1.f / (ol1[0] + src[16 * 64]);
            size_t obase = ((size_t)(b * 2048 + qrow + 16 + l16)) * 1024 + h * 64 + quad * 4;
            #pragma unroll
            for (int dt = 0; dt < 4; ++dt) {
                floatx4 r;
                #pragma unroll
                for (int i = 0; i < 4; ++i) r[i] = o1[dt][i] * inv;
                *(floatx4*)&out[obase + dt * 16] = r;
            }
        }
    }
}

extern "C" void kernel_launch(void* const* d_in, const int* in_sizes, int n_in,
                              void* d_out, int out_size, void* d_ws, size_t ws_size,
                              hipStream_t stream) {
    const float* x      = (const float*)d_in[0];
    const float* coords = (const float*)d_in[1];
    const float* mask   = (const float*)d_in[2];
    const float* Wqkv   = (const float*)d_in[3];
    const float* bqkv   = (const float*)d_in[4];
    const float* rw     = (const float*)d_in[5];
    float* out = (float*)d_out;

    // Workspace layout
    //   xh   : [0,          8,388,608)
    //   maskp: [8,388,608,  16,777,216)
    //   Wt   : [16,777,216, 23,068,672)
    //   qh   : [23,068,672, 31,457,280)
    //   kh   : [31,457,280, 39,845,888)
    //   vt   : [39,845,888, 48,234,496)
    //   esch : [48,234,496, 48,365,568)
    char* ws = (char*)d_ws;
    _Float16* xh    = (_Float16*)(ws);
    _Float16* maskp = (_Float16*)(ws + 8388608);
    _Float16* Wt    = (_Float16*)(ws + 16777216);
    _Float16* qh    = (_Float16*)(ws + 23068672);
    _Float16* kh    = (_Float16*)(ws + 31457280);
    _Float16* vt    = (_Float16*)(ws + 39845888);
    _Float16* esch  = (_Float16*)(ws + 48234496);

    k_prep<<<6400, 256, 0, stream>>>(x, Wqkv, coords, rw, mask, xh, Wt, esch, maskp);
    k_gemm<<<dim3(24, 32), 256, 0, stream>>>(xh, Wt, bqkv, esch, qh, kh, vt);
    k_attn<<<1024, 256, 0, stream>>>(qh, kh, vt, maskp, esch, out);
}

// Round 12
// 177.515 us; speedup vs baseline: 1.2544x; 1.0288x over previous
//
#include <hip/hip_runtime.h>

typedef _Float16 half8 __attribute__((ext_vector_type(8)));
typedef _Float16 half4 __attribute__((ext_vector_type(4)));
typedef _Float16 half2v __attribute__((ext_vector_type(2)));
typedef float floatx4 __attribute__((ext_vector_type(4)));

// Problem constants: B=2, N=2048, D=1024, H=16, C=3, Dh=64
// q pre-scaled by 0.125*LOG2E; mask in log2e units -> softmax = exp2(st+m).
// Coord bias -cp[k] folded multiplicatively: V rows scaled by e^{-cp[k]} (fp16,
// matched exactly in the denominator via the esch MFMA operand).
#define LOG2E 1.44269504088896f
#define QSCALE 0.18033688011112f   // 0.125 * LOG2E

__device__ __forceinline__ void async16(const void* g, void* l) {
    __builtin_amdgcn_global_load_lds(
        (const __attribute__((address_space(1))) unsigned int*)g,
        (__attribute__((address_space(3))) unsigned int*)l, 16, 0, 0);
}
__device__ __forceinline__ half4 pack4(float a, float b, float c, float d) {
    half2v lo = __builtin_bit_cast(half2v, __builtin_amdgcn_cvt_pkrtz(a, b));
    half2v hi = __builtin_bit_cast(half2v, __builtin_amdgcn_cvt_pkrtz(c, d));
    half4 r; r[0] = lo[0]; r[1] = lo[1]; r[2] = hi[0]; r[3] = hi[1];
    return r;
}
__device__ __forceinline__ half8 cat8(half4 lo, half4 hi) {
    half8 r;
    r[0] = lo[0]; r[1] = lo[1]; r[2] = lo[2]; r[3] = lo[3];
    r[4] = hi[0]; r[5] = hi[1]; r[6] = hi[2]; r[7] = hi[3];
    return r;
}

// ---------------- fused prep (R12): convert_x | transpose_w | escale | prep_mask ----------------
// Restructured for coalescing + single occupancy round (grid 6400 -> 2112):
//  [0,256)     convert_x, x8 grid-stride (same 32B/lane coalescing)
//  [256,1024)  transpose_w in 64x64 tiles: loads 256B/wave-row, stores half8
//              (16B/lane vs old 2B/lane - the old 32x32 path was 8x under-coalesced
//              on stores). LDS [64][65] f32: 65 = 1 mod 32 -> <=2-way banks (free).
//  [1024,1088) esch, x4 per thread
//  [1088,2112) prep_mask (unchanged logic)
__global__ __launch_bounds__(256) void k_prep(
    const float* __restrict__ x, const float* __restrict__ W,
    const float* __restrict__ coords, const float* __restrict__ rw,
    const float* __restrict__ mask,
    _Float16* __restrict__ xh, _Float16* __restrict__ Wt,
    _Float16* __restrict__ esch, _Float16* __restrict__ maskp) {
    __shared__ float smem[4352];        // 17.4 KB: mask tile 64x68; transpose 64x65
    int bx = blockIdx.x, tid = threadIdx.x;
    if (bx < 256) {
        // ---- convert x (fp32 -> fp16), 8 half8 units per thread ----
        const floatx4* xin = (const floatx4*)x;
        #pragma unroll
        for (int s = 0; s < 8; ++s) {
            int i = s * 65536 + bx * 256 + tid;
            floatx4 a = xin[i * 2];
            floatx4 b = xin[i * 2 + 1];
            half8 h;
            h[0] = (_Float16)a[0]; h[1] = (_Float16)a[1]; h[2] = (_Float16)a[2]; h[3] = (_Float16)a[3];
            h[4] = (_Float16)b[0]; h[5] = (_Float16)b[1]; h[6] = (_Float16)b[2]; h[7] = (_Float16)b[3];
            *(half8*)&xh[i * 8] = h;
        }
    } else if (bx < 1024) {
        // ---- transpose + convert Wqkv [1024,3072] -> Wt fp16 [3072,1024], 64x64 tiles ----
        int b2 = bx - 256;
        int n0 = (b2 % 48) * 64, k0 = (b2 / 48) * 64;
        int tx = tid & 63, ty = tid >> 6;   // (64,4)
        float (*tile)[65] = (float(*)[65])smem;
        #pragma unroll
        for (int r = 0; r < 16; ++r)
            tile[r * 4 + ty][tx] = W[(size_t)(k0 + r * 4 + ty) * 3072 + n0 + tx];
        __syncthreads();
        int orow = tid >> 3;                // 0..31 (n-row within pass)
        int kc = (tid & 7) * 8;             // 8-wide k chunk
        #pragma unroll
        for (int p = 0; p < 2; ++p) {
            int r = p * 32 + orow;
            half8 h;
            #pragma unroll
            for (int j = 0; j < 8; ++j) h[j] = (_Float16)tile[kc + j][r];
            *(half8*)&Wt[(size_t)(n0 + r) * 1024 + k0 + kc] = h;
        }
    } else if (bx < 1088) {
        // ---- esch[b,h,n] = fp16( exp2(-LOG2E * sum_c coords*rw) ), x4 ----
        #pragma unroll
        for (int s = 0; s < 4; ++s) {
            int idx = (bx - 1024) * 1024 + s * 256 + tid;
            int bh = idx >> 11, n = idx & 2047;
            int b = bh >> 4, h = bh & 15;
            const float* c = &coords[(b * 2048 + n) * 3];
            const float* w = &rw[h * 3];
            float v = -LOG2E * (c[0] * w[0] + c[1] * w[1] + c[2] * w[2]);
            esch[idx] = (_Float16)__builtin_amdgcn_exp2f(v);
        }
    } else {
        // ---- mask -> fp16*LOG2E, S^T MFMA C-fragment layout ----
        int bid = bx - 1088;
        int qt = bid >> 5, kt = bid & 31;
        int row0 = qt * 64, col0 = kt * 64;
        int lr = tid >> 2, lc = (tid & 3) * 16;
        #pragma unroll
        for (int j = 0; j < 4; ++j)
            *(floatx4*)&smem[lr * 68 + lc + j * 4] =
                *(const floatx4*)&mask[(size_t)(row0 + lr) * 2048 + col0 + lc + j * 4];
        __syncthreads();
        int w = tid >> 6, lane = tid & 63, quad = lane >> 4, l16 = lane & 15;
        half4* outp = (half4*)maskp + (size_t)((qt * 32 + kt) * 4 + w) * 256 + lane;
        #pragma unroll
        for (int t = 0; t < 4; ++t) {
            floatx4 m = *(const floatx4*)&smem[(w * 16 + l16) * 68 + t * 16 + quad * 4];
            outp[t * 64] = pack4(m[0] * LOG2E, m[1] * LOG2E, m[2] * LOG2E, m[3] * LOG2E);
        }
    }
}

// ---------------- fused QKV GEMM: BK=64 (m97 config), double-buffered async staging ----------------
__global__ __launch_bounds__(256) void k_gemm(
    const _Float16* __restrict__ Ah, const _Float16* __restrict__ Bt,
    const float* __restrict__ bias, const _Float16* __restrict__ esch,
    _Float16* __restrict__ qh, _Float16* __restrict__ kh, _Float16* __restrict__ vt) {
    __shared__ _Float16 smem[32768];   // 2 bufs x (As 8192 + Bs 8192) halves = 64 KB
    int tid = threadIdx.x;
    int w = tid >> 6, lane = tid & 63;
    int quad = lane >> 4, l16 = lane & 15;
    int m0 = blockIdx.y * 128;
    int n0 = blockIdx.x * 128;
    bool QK = n0 < 2048;
    int mq = (w >> 1) * 64, nq = (w & 1) * 64;
    int c0 = n0 + nq;

    int rl8 = lane >> 3;            // row within 8-row staging chunk
    int pb8 = lane & 7;             // physical 16B block within 128B row
    floatx4 acc[4][4] = {};

    const _Float16* ap[4];
    const _Float16* bp[4];
    #pragma unroll
    for (int j = 0; j < 4; ++j) {
        int row = w * 32 + j * 8 + rl8;
        int lb = pb8 ^ (row & 7);
        ap[j] = Ah + (size_t)(m0 + row) * 1024 + lb * 8;
        bp[j] = Bt + (size_t)(n0 + row) * 1024 + lb * 8;
    }

    #define GSTAGE(buf) {                                      \
        _Float16* As_ = smem + (buf) * 16384;                  \
        _Float16* Bs_ = As_ + 8192;                            \
        _Pragma("unroll")                                      \
        for (int j = 0; j < 4; ++j) {                          \
            async16(ap[j], &As_[(w * 32 + j * 8) * 64]);       \
            ap[j] += 64;                                       \
        }                                                      \
        _Pragma("unroll")                                      \
        for (int j = 0; j < 4; ++j) {                          \
            async16(bp[j], &Bs_[(w * 32 + j * 8) * 64]);       \
            bp[j] += 64;                                       \
        }                                                      \
    }

    #define GHALF(As_, Bs_, cblk) {                                                   \
        half8 af[4], bf[4];                                                            \
        _Pragma("unroll")                                                              \
        for (int s = 0; s < 4; ++s) {                                                  \
            int ra = mq + s * 16 + l16;                                                \
            af[s] = *(const half8*)&As_[ra * 64 + ((((cblk) | quad) ^ (ra & 7)) << 3)]; \
            int rb = nq + s * 16 + l16;                                                \
            bf[s] = *(const half8*)&Bs_[rb * 64 + ((((cblk) | quad) ^ (rb & 7)) << 3)]; \
        }                                                                              \
        if (QK) {                                                                      \
            _Pragma("unroll")                                                          \
            for (int ms = 0; ms < 4; ++ms)                                             \
                _Pragma("unroll")                                                      \
                for (int ns = 0; ns < 4; ++ns)                                         \
                    acc[ms][ns] = __builtin_amdgcn_mfma_f32_16x16x32_f16(              \
                        bf[ns], af[ms], acc[ms][ns], 0, 0, 0);                         \
        } else {                                                                       \
            _Pragma("unroll")                                                          \
            for (int ms = 0; ms < 4; ++ms)                                             \
                _Pragma("unroll")                                                      \
                for (int ns = 0; ns < 4; ++ns)                                         \
                    acc[ms][ns] = __builtin_amdgcn_mfma_f32_16x16x32_f16(              \
                        af[ms], bf[ns], acc[ms][ns], 0, 0, 0);                         \
        }                                                                              \
    }

    #define GBODY(cur, last) {                                                         \
        __syncthreads();                                                               \
        if (!(last)) GSTAGE((cur) ^ 1);                                                \
        const _Float16* As_ = smem + (cur) * 16384;                                    \
        const _Float16* Bs_ = As_ + 8192;                                              \
        GHALF(As_, Bs_, 0);                                                            \
        GHALF(As_, Bs_, 4);                                                            \
    }

    GSTAGE(0);
    #pragma unroll 1
    for (int kt2 = 0; kt2 < 7; ++kt2) {
        GBODY(0, false);
        GBODY(1, false);
    }
    GBODY(0, false);
    GBODY(1, true);
    #undef GBODY
    #undef GHALF
    #undef GSTAGE

    __syncthreads();   // all waves done reading staging before slab reuse

    // ---- epilogue: wave-private 32x72 slab, 2 passes, coalesced half8 stores ----
    _Float16* Ls = smem + w * 2304;
    int rl = lane >> 3, pb = lane & 7;
    int b = (m0 + mq) >> 11, nbase = (m0 + mq) & 2047;
    if (QK) {
        float qsc = (c0 < 1024) ? QSCALE : 1.0f;    // q heads pre-scaled for softmax
        int h2 = c0 >> 6;                           // 0..31: q heads then k heads
        _Float16* dst = (h2 < 16 ? qh : kh) + (size_t)(((b << 4) + (h2 & 15)) * 2048) * 64;
        int d0 = pb << 3;
        #pragma unroll
        for (int p = 0; p < 2; ++p) {
            #pragma unroll
            for (int ns = 0; ns < 4; ++ns) {
                floatx4 b4 = *(const floatx4*)&bias[c0 + ns * 16 + quad * 4];
                #pragma unroll
                for (int m2 = 0; m2 < 2; ++m2) {
                    int ms = p * 2 + m2;
                    floatx4 v;
                    #pragma unroll
                    for (int i = 0; i < 4; ++i) v[i] = (acc[ms][ns][i] + b4[i]) * qsc;
                    *(half4*)&Ls[(m2 * 16 + l16) * 72 + ns * 16 + quad * 4] =
                        pack4(v[0], v[1], v[2], v[3]);
                }
            }
            #pragma unroll
            for (int rep = 0; rep < 4; ++rep) {
                int nl = rep * 8 + rl;
                half8 v = *(const half8*)&Ls[nl * 72 + d0];
                *(half8*)&dst[(size_t)(nbase + p * 32 + nl) * 64 + d0] = v;
            }
        }
    } else {
        int h = (c0 - 2048) >> 6;
        _Float16* dst = vt + (size_t)(((b << 4) + h) * 64) * 2048;
        // V rows scaled by e^{-cp[b,h,n]} in fp32 (single fp16 rounding, matched
        // bit-exactly with the attention denominator which uses the same fp16 esch).
        const _Float16* ePtr = esch + (size_t)((b << 4) + h) * 2048 + nbase + quad * 4;
        float ef[4][4];
        #pragma unroll
        for (int ms = 0; ms < 4; ++ms) {
            half4 e4 = *(const half4*)&ePtr[ms * 16];
            #pragma unroll
            for (int i = 0; i < 4; ++i) ef[ms][i] = (float)e4[i];
        }
        int noff = pb << 3;
        #pragma unroll
        for (int p = 0; p < 2; ++p) {
            #pragma unroll
            for (int n2 = 0; n2 < 2; ++n2) {
                int ns = p * 2 + n2;
                float bv = bias[c0 + ns * 16 + l16];
                #pragma unroll
                for (int ms = 0; ms < 4; ++ms) {
                    *(half4*)&Ls[(n2 * 16 + l16) * 72 + ms * 16 + quad * 4] =
                        pack4((acc[ms][ns][0] + bv) * ef[ms][0],
                              (acc[ms][ns][1] + bv) * ef[ms][1],
                              (acc[ms][ns][2] + bv) * ef[ms][2],
                              (acc[ms][ns][3] + bv) * ef[ms][3]);
                }
            }
            #pragma unroll
            for (int rep = 0; rep < 4; ++rep) {
                int cl = rep * 8 + rl;
                half8 v = *(const half8*)&Ls[cl * 72 + noff];
                *(half8*)&dst[(size_t)(p * 32 + cl) * 2048 + nbase + noff] = v;
            }
        }
    }
}

// ---------------- flash attention: split-K, 256 thr, KVBLK=32, counted-vmcnt barriers ----------------
// (byte-identical to R9/R11's k_attn: 62 us, passing)
__global__ __launch_bounds__(256) __attribute__((amdgpu_waves_per_eu(4, 4)))
void k_attn(
    const _Float16* __restrict__ qh, const _Float16* __restrict__ kh,
    const _Float16* __restrict__ vt, const _Float16* __restrict__ maskp,
    const _Float16* __restrict__ esch, float* __restrict__ out) {
    __shared__ _Float16 KV[2][2][4096];   // [group][buf]: K [0,2048), V [2048,4096); 32 KB
    __shared__ _Float16 es[2048];         // esch slice for this bh (4 KB)
    int tid = threadIdx.x;
    int w = tid >> 6, lane = tid & 63;
    int g2 = w >> 1, wq = w & 1;          // k-group, q-sub-block
    int quad = lane >> 4, l16 = lane & 15;
    int bid = blockIdx.x;
    int qt3 = bid & 31, bh = bid >> 5;
    int b = bh >> 4, h = bh & 15;
    int qrow = qt3 * 64 + wq * 32;

    // stage esch slice to LDS (visible after the first body's full barrier)
    *(half8*)&es[tid * 8] = *(const half8*)&esch[(size_t)bh * 2048 + tid * 8];

    half8 qf[2][2];
    #pragma unroll
    for (int g = 0; g < 2; ++g) {
        const _Float16* qp = &qh[((size_t)bh * 2048 + qrow + g * 16 + l16) * 64];
        qf[g][0] = *(const half8*)&qp[quad * 8];
        qf[g][1] = *(const half8*)&qp[32 + quad * 8];
    }
    floatx4 o0[4] = {}, o1[4] = {};
    floatx4 ol0 = {}, ol1 = {};        // denominator accumulators (esch-weighted)

    // K staging: 32 rows x 64 cols per tile; wave stages 16 rows (2 asyncs of 8)
    int rl = lane >> 3, pb = lane & 7;
    int swk = (pb ^ rl) << 3;
    const _Float16* kp0 = kh + (size_t)bh * 131072
        + (size_t)(g2 * 1024 + wq * 16 + rl) * 64 + swk;
    const _Float16* kp1 = kp0 + 512;                 // +8 k rows
    // V staging: [d=64][n=32], packed as 32 super-rows of 128B (d pairs),
    // XOR-swizzled over 8 x 16B slots; wave stages 16 super-rows (2 asyncs of 8)
    int lbs = pb ^ (rl & 7);                         // logical block at this slot
    const _Float16* vp0 = vt + (size_t)bh * 131072
        + (size_t)(wq * 32 + 2 * rl + (lbs >> 2)) * 2048 + g2 * 1024 + ((lbs & 3) << 3);
    const _Float16* vp1 = vp0 + 16 * 2048;           // +8 super-rows (=16 d rows)
    // mask fragment pointers: frag block = ((qt3*32 + kt_old)*4 + w16)*256 + lane,
    // w16 = wq*2 + g; per body (32 k cols) advance alternates +128 / +896
    const half4* mp0 = (const half4*)maskp +
        ((size_t)(qt3 * 32 + g2 * 16) * 4 + wq * 2 + 0) * 256 + lane;
    const half4* mp1 = (const half4*)maskp +
        ((size_t)(qt3 * 32 + g2 * 16) * 4 + wq * 2 + 1) * 256 + lane;
    int ecur = g2 * 1024 + quad * 4;      // LDS esch cursor (advances 32/body)

    half4 mC0[2], mC1[2];                 // single-set mask prefetch (2 frags/group)

    #define STAGE(buf) {                                             \
        async16(kp0, &KV[g2][buf][wq * 1024]);                       \
        async16(kp1, &KV[g2][buf][wq * 1024 + 512]);                 \
        async16(vp0, &KV[g2][buf][2048 + wq * 1024]);                \
        async16(vp1, &KV[g2][buf][2048 + wq * 1024 + 512]);          \
        kp0 += 2048; kp1 += 2048; vp0 += 32; vp1 += 32;              \
    }

    #define MPREF(d) {                                               \
        mC0[0] = mp0[0]; mC0[1] = mp0[64];                           \
        mC1[0] = mp1[0]; mC1[1] = mp1[64];                           \
        mp0 += (d); mp1 += (d);                                      \
    }

    #define BODY(cur, last, md, full) {                                                \
        if (full) {                                                                    \
            __syncthreads();                                                           \
        } else {                                                                       \
            asm volatile("s_waitcnt vmcnt(4)" ::: "memory");                           \
            __builtin_amdgcn_s_barrier();                                              \
        }                                                                              \
        __builtin_amdgcn_sched_barrier(0);  /* nothing crosses the barrier */          \
        if (!(last)) STAGE((cur) ^ 1);                                                 \
        __builtin_amdgcn_sched_barrier(0);  /* STAGE loads issue before all else */    \
        const _Float16* Ksc = &KV[g2][cur][0];                                         \
        const _Float16* Vsc = &KV[g2][cur][2048];                                      \
        half4 ptl[2][2];                                                               \
        _Pragma("unroll")                                                              \
        for (int t = 0; t < 2; ++t) {                                                  \
            int r = t * 16 + l16;                                                      \
            half8 k0 = *(const half8*)&Ksc[r * 64 + ((quad ^ (r & 7)) << 3)];          \
            half8 k1 = *(const half8*)&Ksc[r * 64 + (((quad + 4) ^ (r & 7)) << 3)];    \
            {                                                                          \
                half4 ml = mC0[t];                                                     \
                floatx4 z;                                                             \
                z[0] = (float)ml[0]; z[1] = (float)ml[1];                              \
                z[2] = (float)ml[2]; z[3] = (float)ml[3];                              \
                z = __builtin_amdgcn_mfma_f32_16x16x32_f16(k0, qf[0][0], z, 0, 0, 0);  \
                z = __builtin_amdgcn_mfma_f32_16x16x32_f16(k1, qf[0][1], z, 0, 0, 0);  \
                ptl[0][t] = pack4(__builtin_amdgcn_exp2f(z[0]),                        \
                                  __builtin_amdgcn_exp2f(z[1]),                        \
                                  __builtin_amdgcn_exp2f(z[2]),                        \
                                  __builtin_amdgcn_exp2f(z[3]));                       \
            }                                                                          \
            {                                                                          \
                half4 ml = mC1[t];                                                     \
                floatx4 z;                                                             \
                z[0] = (float)ml[0]; z[1] = (float)ml[1];                              \
                z[2] = (float)ml[2]; z[3] = (float)ml[3];                              \
                z = __builtin_amdgcn_mfma_f32_16x16x32_f16(k0, qf[1][0], z, 0, 0, 0);  \
                z = __builtin_amdgcn_mfma_f32_16x16x32_f16(k1, qf[1][1], z, 0, 0, 0);  \
                ptl[1][t] = pack4(__builtin_amdgcn_exp2f(z[0]),                        \
                                  __builtin_amdgcn_exp2f(z[1]),                        \
                                  __builtin_amdgcn_exp2f(z[2]),                        \
                                  __builtin_amdgcn_exp2f(z[3]));                       \
            }                                                                          \
        }                                                                              \
        if (!(last)) MPREF(md);                                                        \
        half8 pt8_0 = cat8(ptl[0][0], ptl[0][1]);                                      \
        half8 pt8_1 = cat8(ptl[1][0], ptl[1][1]);                                      \
        {                                                                              \
            half4 e0 = *(const half4*)&es[ecur];                                       \
            half4 e1 = *(const half4*)&es[ecur + 16];                                  \
            half8 ev = cat8(e0, e1);                                                   \
            ol0 = __builtin_amdgcn_mfma_f32_16x16x32_f16(ev, pt8_0, ol0, 0, 0, 0);     \
            ol1 = __builtin_amdgcn_mfma_f32_16x16x32_f16(ev, pt8_1, ol1, 0, 0, 0);     \
        }                                                                              \
        ecur += 32;                                                                    \
        _Pragma("unroll")                                                              \
        for (int dt = 0; dt < 4; ++dt) {                                               \
            int rv = dt * 16 + l16;                                                    \
            int sr = rv >> 1;                                                          \
            int lb0 = ((rv & 1) << 2) | (quad >> 1);                                   \
            half4 vlo = *(const half4*)&Vsc[sr * 64 +                                  \
                ((lb0 ^ (sr & 7)) << 3) + ((quad & 1) << 2)];                          \
            half4 vhi = *(const half4*)&Vsc[sr * 64 +                                  \
                (((lb0 | 2) ^ (sr & 7)) << 3) + ((quad & 1) << 2)];                    \
            half8 vf = cat8(vlo, vhi);                                                 \
            o0[dt] = __builtin_amdgcn_mfma_f32_16x16x32_f16(vf, pt8_0, o0[dt], 0, 0, 0); \
            o1[dt] = __builtin_amdgcn_mfma_f32_16x16x32_f16(vf, pt8_1, o1[dt], 0, 0, 0); \
        }                                                                              \
    }

    STAGE(0);
    MPREF(128);
    BODY(0, false, 896, 1);   // first body: full sync (drains es ds_write + q loads)
    BODY(1, false, 128, 0);
    #pragma unroll 1
    for (int kt2 = 0; kt2 < 14; ++kt2) {
        BODY(0, false, 896, 0);
        BODY(1, false, 128, 0);
    }
    BODY(0, false, 896, 0);
    BODY(1, true, 0, 0);
    #undef BODY
    #undef MPREF
    #undef STAGE

    // ---- combine partials across the wave pair (w, w^2) via LDS ----
    __syncthreads();                       // full drain: everyone done reading staging
    float* comb = (float*)KV;              // 4 waves x 17 idx x 64 lanes = 17.4 KB
    {
        float* dst = comb + ((size_t)w * 17) * 64 + lane;
        if (g2 == 0) {                     // group 0 exports o1/ol1
            #pragma unroll
            for (int dt = 0; dt < 4; ++dt)
                #pragma unroll
                for (int i = 0; i < 4; ++i)
                    dst[(dt * 4 + i) * 64] = o1[dt][i];
            dst[16 * 64] = ol1[0];
        } else {                           // group 1 exports o0/ol0
            #pragma unroll
            for (int dt = 0; dt < 4; ++dt)
                #pragma unroll
                for (int i = 0; i < 4; ++i)
                    dst[(dt * 4 + i) * 64] = o0[dt][i];
            dst[16 * 64] = ol0[0];
        }
    }
    __syncthreads();
    {
        const float* src = comb + ((size_t)(w ^ 2) * 17) * 64 + lane;
        if (g2 == 0) {
            // sum own o0 with partner's o0 -> store q-group 0 (rows qrow + l16)
            #pragma unroll
            for (int dt = 0; dt < 4; ++dt)
                #pragma unroll
                for (int i = 0; i < 4; ++i)
                    o0[dt][i] += src[(dt * 4 + i) * 64];
            float inv = 1.f / (ol0[0] + src[16 * 64]);
            size_t obase = ((size_t)(b * 2048 + qrow + l16)) * 1024 + h * 64 + quad * 4;
            #pragma unroll
            for (int dt = 0; dt < 4; ++dt) {
                floatx4 r;
                #pragma unroll
                for (int i = 0; i < 4; ++i) r[i] = o0[dt][i] * inv;
                *(floatx4*)&out[obase + dt * 16] = r;
            }
        } else {
            // sum own o1 with partner's o1 -> store q-group 1 (rows qrow + 16 + l16)
            #pragma unroll
            for (int dt = 0; dt < 4; ++dt)
                #pragma unroll
                for (int i = 0; i < 4; ++i)
                    o1[dt][i] += src[(dt * 4 + i) * 64];
            float inv = 1.f / (ol1[0] + src[16 * 64]);
            size_t obase = ((size_t)(b * 2048 + qrow + 16 + l16)) * 1024 + h * 64 + quad * 4;
            #pragma unroll
            for (int dt = 0; dt < 4; ++dt) {
                floatx4 r;
                #pragma unroll
                for (int i = 0; i < 4; ++i) r[i] = o1[dt][i] * inv;
                *(floatx4*)&out[obase + dt * 16] = r;
            }
        }
    }
}

extern "C" void kernel_launch(void* const* d_in, const int* in_sizes, int n_in,
                              void* d_out, int out_size, void* d_ws, size_t ws_size,
                              hipStream_t stream) {
    const float* x      = (const float*)d_in[0];
    const float* coords = (const float*)d_in[1];
    const float* mask   = (const float*)d_in[2];
    const float* Wqkv   = (const float*)d_in[3];
    const float* bqkv   = (const float*)d_in[4];
    const float* rw     = (const float*)d_in[5];
    float* out = (float*)d_out;

    // Workspace layout
    //   xh   : [0,          8,388,608)
    //   maskp: [8,388,608,  16,777,216)
    //   Wt   : [16,777,216, 23,068,672)
    //   qh   : [23,068,672, 31,457,280)
    //   kh   : [31,457,280, 39,845,888)
    //   vt   : [39,845,888, 48,234,496)
    //   esch : [48,234,496, 48,365,568)
    char* ws = (char*)d_ws;
    _Float16* xh    = (_Float16*)(ws);
    _Float16* maskp = (_Float16*)(ws + 8388608);
    _Float16* Wt    = (_Float16*)(ws + 16777216);
    _Float16* qh    = (_Float16*)(ws + 23068672);
    _Float16* kh    = (_Float16*)(ws + 31457280);
    _Float16* vt    = (_Float16*)(ws + 39845888);
    _Float16* esch  = (_Float16*)(ws + 48234496);

    k_prep<<<2112, 256, 0, stream>>>(x, Wqkv, coords, rw, mask, xh, Wt, esch, maskp);
    k_gemm<<<dim3(24, 32), 256, 0, stream>>>(xh, Wt, bqkv, esch, qh, kh, vt);
    k_attn<<<1024, 256, 0, stream>>>(qh, kh, vt, maskp, esch, out);
}